// Round 7
// baseline (1930.194 us; speedup 1.0000x reference)
//
#include <hip/hip_runtime.h>

#define B_   64
#define T_   4096
#define HID_ 128

typedef float f32x4 __attribute__((ext_vector_type(4)));
typedef short s16x8 __attribute__((ext_vector_type(8)));
typedef short s16x4 __attribute__((ext_vector_type(4)));

__device__ __forceinline__ float fexp2(float x){ float r; asm("v_exp_f32 %0, %1":"=v"(r):"v"(x)); return r; }
__device__ __forceinline__ float frcp (float x){ float r; asm("v_rcp_f32 %0, %1":"=v"(r):"v"(x)); return r; }
__device__ __forceinline__ unsigned short f2bf(float f){
    unsigned u = __float_as_uint(f);
    u += 0x7FFFu + ((u >> 16) & 1u);      // round-to-nearest-even
    return (unsigned short)(u >> 16);
}
__device__ __forceinline__ float sigf(float x){
    return frcp(1.0f + fexp2(-1.44269504089f * x));
}
// barrier that drains LDS only (no vmcnt) — global prefetch/stores fly across steps
__device__ __forceinline__ void bar_lgkm(){
    asm volatile("s_waitcnt lgkmcnt(0)\ns_barrier" ::: "memory");
    __builtin_amdgcn_sched_barrier(0);
}

// ---------------- Phase 1: ODE features -> feats[B][T][32] bf16 (PERMUTED) ----
__global__ __launch_bounds__(256) void k_feats(
    const float* __restrict__ x, const float* __restrict__ u,
    const float* __restrict__ dtp, const float* __restrict__ theta,
    const float* __restrict__ He, const float* __restrict__ taue,
    const float* __restrict__ Hi, const float* __restrict__ taui,
    const float* __restrict__ l1, const float* __restrict__ l2,
    const float* __restrict__ l3, const float* __restrict__ l4,
    const float* __restrict__ Cf, const float* __restrict__ Cl,
    const float* __restrict__ Cu, const float* __restrict__ Cb,
    unsigned short* __restrict__ feats)
{
    long idx = (long)blockIdx.x * 256 + threadIdx.x;   // b*T + t
    const float dt = dtp[0];
    const float th00 = theta[0], th01 = theta[1], th10 = theta[2], th11 = theta[3];
    const float he = He[0], te = taue[0], hi = Hi[0], ti = taui[0];
    const float L1 = l1[0], L2v = l2[0], L3 = l3[0], L4 = l4[0];
    float cf[4], cl[4], cu[4], cb[4];
    #pragma unroll
    for (int i = 0; i < 4; ++i){ cf[i]=Cf[i]; cl[i]=Cl[i]; cu[i]=Cu[i]; cb[i]=Cb[i]; }
    const float ite  = 1.f/te, iti = 1.f/ti;
    const float He_te = he*ite, ite2 = ite*ite;
    const float Hi_ti = hi*iti, iti2 = iti*iti;

    float X[22];
    const float2* xr = (const float2*)(x + idx*22);
    #pragma unroll
    for (int i = 0; i < 11; ++i){ float2 v = xr[i]; X[2*i] = v.x; X[2*i+1] = v.y; }
    float2 uv = ((const float2*)u)[idx];

    float xt0 = X[0]*th00 + X[1]*th10;
    float xt1 = X[0]*th01 + X[1]*th11;
    float ut0 = uv.x*th00 + uv.y*th10;
    float ut1 = uv.x*th01 + uv.y*th11;
    float s0 = sigf(xt0), s1 = sigf(xt1);

    float Mf00 = cf[0]+cl[0]+L1, Mf01 = cf[1]+cl[1], Mf10 = cf[2]+cl[2], Mf11 = cf[3]+cl[3]+L1;
    float Af0 = Mf00*s0 + Mf01*s1, Af1 = Mf10*s0 + Mf11*s1;
    float Au0 = cu[0]*ut0 + cu[1]*ut1, Au1 = cu[2]*ut0 + cu[3]*ut1;
    float Mb00 = cb[0]+cl[0], Mb01 = cb[1]+cl[1], Mb10 = cb[2]+cl[2], Mb11 = cb[3]+cl[3];
    float Abl0 = Mb00*s0 + Mb01*s1, Abl1 = Mb10*s0 + Mb11*s1;
    float A30 = (Mb00+L3)*s0 + Mb01*s1,  A31 = Mb10*s0 + (Mb11+L3)*s1;

    float F[22];
    F[0]  = X[0]  + dt*(X[10]-X[12]);
    F[1]  = X[1]  + dt*(X[11]-X[13]);
    F[2]  = X[2]  + dt*X[8];
    F[3]  = X[3]  + dt*X[9];
    F[4]  = X[4]  + dt*X[10];
    F[5]  = X[5]  + dt*X[11];
    F[6]  = X[6]  + dt*X[12];
    F[7]  = X[7]  + dt*X[13];
    F[8]  = X[8]  + dt*(He_te*(Af0+Au0) - 2.f*X[8]*ite  - X[2]*ite2);
    F[9]  = X[9]  + dt*(He_te*(Af1+Au1) - 2.f*X[9]*ite  - X[3]*ite2);
    F[10] = X[10] + dt*(He_te*(Abl0 + L2v*sigf(X[6])) - 2.f*X[10]*ite - X[4]*ite2);
    F[11] = X[11] + dt*(He_te*(Abl1 + L2v*sigf(X[7])) - 2.f*X[11]*ite - X[5]*ite2);
    F[12] = X[12] + dt*(Hi_ti*L4*sigf(X[14]) - 2.f*X[12]*iti - X[6]*iti2);
    F[13] = X[13] + dt*(Hi_ti*L4*sigf(X[15]) - 2.f*X[13]*iti - X[7]*iti2);
    F[14] = X[14] + dt*X[16];
    F[15] = X[15] + dt*X[17];
    F[16] = X[16] + dt*(He_te*A30 - 2.f*X[16]*ite - X[14]*ite2);
    F[17] = X[17] + dt*(He_te*A31 - 2.f*X[17]*ite - X[15]*ite2);
    F[18] = X[18]; F[19] = X[19]; F[20] = X[20]; F[21] = X[21];

    unsigned short op[32];
    #pragma unroll
    for (int s = 0; s < 4; ++s){
        #pragma unroll
        for (int e = 0; e < 8; ++e){
            int j = s*4 + (e & 3) + ((e >> 2) << 4);
            op[s*8+e] = (j < 22) ? f2bf(F[j]) : (unsigned short)0;
        }
    }
    uint4* dst = (uint4*)(feats + idx*32);
    #pragma unroll
    for (int q = 0; q < 4; ++q){
        uint4 v;
        v.x = (unsigned)op[q*8+0] | ((unsigned)op[q*8+1] << 16);
        v.y = (unsigned)op[q*8+2] | ((unsigned)op[q*8+3] << 16);
        v.z = (unsigned)op[q*8+4] | ((unsigned)op[q*8+5] << 16);
        v.w = (unsigned)op[q*8+6] | ((unsigned)op[q*8+7] << 16);
        dst[q] = v;
    }
}

// ---------------- Phase 2: LSTM scan, fully diluted schedule ----------------
// 16 blocks x 4 batches, 8 waves; wave w owns j in [w*16, w*16+16).
// Per step s of a 16-step chunk:
//   - write G_f pending (computed 4 steps ago) -> gfb slot (dead after its read)
//   - 1 G_f MFMA for NEXT chunk (reg-resident A-frag: fills pipe during h-read head)
//   - 4 h ds_read_b128 -> 16 h-MFMAs -> act -> h write -> lgkm barrier
// Chunk boundary: fch store (feats k+1), y-GEMM(k-1) on waves 4-7, 1 barrier.
// gfb stride 516 dwords (bank spread); LDS total ~154.6 KB.
__global__ __launch_bounds__(512, 1) void k_scan(
    const unsigned short* __restrict__ feats,
    const float* __restrict__ Wih, const float* __restrict__ Whh,
    const float* __restrict__ bih, const float* __restrict__ bhh,
    const float* __restrict__ Wlin, const float* __restrict__ blin,
    float* __restrict__ out)
{
    __shared__ __align__(16) unsigned short hist[16 * 576];   // 18.4 KB
    __shared__ __align__(16) unsigned short fch[64 * 32];     // 4 KB (feats of chunk k+1)
    __shared__ __align__(16) float gfb[64 * 516];             // 132 KB G_f (padded stride)

    const int tid = threadIdx.x;
    const int w  = tid >> 6;
    const int l  = tid & 63;
    const int lm = l & 15;
    const int lg = l >> 4;
    const int gb0 = blockIdx.x * 4;
    const int ar  = lm >> 2;

    for (int i = tid; i < 16*576/2; i += 512) ((unsigned*)hist)[i] = 0u;

    // ---- weight B-fragments (bf16) ----
    const int nj = w*16 + lm;
    s16x8 bw[4][5];
    #pragma unroll
    for (int t4 = 0; t4 < 4; ++t4){
        int n = t4*128 + nj;
        #pragma unroll
        for (int kc = 0; kc < 5; ++kc){
            #pragma unroll
            for (int j = 0; j < 8; ++j){
                int k = kc*32 + lg*4 + (j & 3) + ((j >> 2) << 4);
                float wv = 0.f;
                if (kc == 0){ if (k < 22) wv = Wih[n*22 + k]; }
                else        { wv = Whh[n*128 + (k - 32)]; }
                bw[t4][kc][j] = (short)f2bf(wv);
            }
        }
    }
    s16x8 wlf[4];
    #pragma unroll
    for (int kc = 0; kc < 4; ++kc){
        #pragma unroll
        for (int j = 0; j < 8; ++j){
            int k = kc*32 + lg*4 + (j & 3) + ((j >> 2) << 4);
            wlf[kc][j] = (lm < 2) ? (short)f2bf(Wlin[lm*128 + k]) : (short)0;
        }
    }
    const float blv = blin[l & 1];

    const float L2E = 1.44269504089f;
    float nLb0, nLb1, nLb3, b2g;
    {
        float bi = bih[0*128+nj] + bhh[0*128+nj];
        float bf = bih[1*128+nj] + bhh[1*128+nj];
        float bg = bih[2*128+nj] + bhh[2*128+nj];
        float bo = bih[3*128+nj] + bhh[3*128+nj];
        nLb0 = -L2E*bi; nLb1 = -L2E*bf; nLb3 = -L2E*bo; b2g = 2.f*L2E*bg;
    }

    // offsets
    const int aoff = ar*144 + lg*8;                   // h A-frag (shorts) within a hist slot
    const int khc = nj >> 5;
    const int hwoff = lg*144 + (khc*4 + ((nj >> 2) & 3))*8 + ((nj >> 4) & 1)*4 + (nj & 3);
    const float* gfrB = gfb + lg*516 + nj*4;          // gf read base (+ s*4*516/step)
    float* const gwB  = gfb + (4*lg)*516 + nj*4;      // G_f write base (+ (16mt+r)*516 + gate)

    // feats staging: threads < 256 own one 16B unit of the 4KB chunk
    const int u_t = tid >> 4, u_b = (tid >> 2) & 3, u_q = tid & 3;
    const unsigned short* psrc = feats + ((long)(gb0 + u_b)*T_ + u_t)*32 + u_q*8;
    unsigned short* const pdst = fch + (u_t*4 + u_b)*32 + u_q*8;

    const f32x4 Z4 = {0.f, 0.f, 0.f, 0.f};

    // ---- prologue: stage feats(0), burst-compute G_f(chunk 0) ----
    if (tid < 256){ uint4 t0 = *(const uint4*)psrc; *(uint4*)pdst = t0; }
    __syncthreads();
    #pragma unroll
    for (int mt = 0; mt < 4; ++mt){
        s16x8 af = *(const s16x8*)(fch + (mt*16 + lm)*32 + lg*8);
        f32x4 m0 = __builtin_amdgcn_mfma_f32_16x16x32_bf16(af, bw[0][0], Z4, 0,0,0);
        f32x4 m1 = __builtin_amdgcn_mfma_f32_16x16x32_bf16(af, bw[1][0], Z4, 0,0,0);
        f32x4 m2 = __builtin_amdgcn_mfma_f32_16x16x32_bf16(af, bw[2][0], Z4, 0,0,0);
        f32x4 m3 = __builtin_amdgcn_mfma_f32_16x16x32_bf16(af, bw[3][0], Z4, 0,0,0);
        #pragma unroll
        for (int r = 0; r < 4; ++r){
            f32x4 v = {m0[r], m1[r], m2[r], m3[r]};
            *(f32x4*)(gwB + (16*mt + r)*516) = v;
        }
    }
    uint4 pend = {0,0,0,0};
    if (tid < 256) pend = *(const uint4*)(psrc + (long)1*16*32);   // feats(chunk 1)
    __syncthreads();

    f32x4 p[4] = {Z4, Z4, Z4, Z4};     // pending G_f (static-indexed via unroll)
    s16x8 afg = {0,0,0,0,0,0,0,0};
    float c = 0.f;
    const int NCHK = T_/16;

    for (int chk = 0; chk < NCHK; ++chk){
        // ---- boundary ----
        if (tid < 256) *(uint4*)pdst = pend;           // fch = feats(chk+1)
        if (w >= 4 && chk > 0){                        // y for chunk chk-1
            const int mt = w - 4;
            const unsigned short* ap = hist + (mt*4 + (lm>>2))*576 + (lm&3)*144 + lg*8;
            s16x8 q0 = *(const s16x8*)(ap +  0);
            s16x8 q1 = *(const s16x8*)(ap + 32);
            s16x8 q2 = *(const s16x8*)(ap + 64);
            s16x8 q3 = *(const s16x8*)(ap + 96);
            f32x4 acc = __builtin_amdgcn_mfma_f32_16x16x32_bf16(q0, wlf[0], Z4, 0,0,0);
            acc = __builtin_amdgcn_mfma_f32_16x16x32_bf16(q1, wlf[1], acc, 0,0,0);
            acc = __builtin_amdgcn_mfma_f32_16x16x32_bf16(q2, wlf[2], acc, 0,0,0);
            acc = __builtin_amdgcn_mfma_f32_16x16x32_bf16(q3, wlf[3], acc, 0,0,0);
            if (lm < 2){
                const int tY = (chk - 1)*16 + mt*4 + lg;
                #pragma unroll
                for (int r = 0; r < 4; ++r)
                    out[((long)(gb0 + r)*T_ + tY)*2 + lm] = acc[r] + blv;
            }
        }
        bar_lgkm();
        {   // issue next chunk's feats loads (fly across whole chunk)
            long nk = (chk < NCHK-2) ? (chk + 2) : (NCHK-1);
            if (tid < 256) pend = *(const uint4*)(psrc + nk*16*32);
        }
        afg = *(const s16x8*)(fch + (0*16 + lm)*32 + lg*8);   // A-frag for mt=0

        #pragma unroll
        for (int s = 0; s < 16; ++s){
            // 1. write pending G_f (computed at step s-4; chunk-0 early steps skip)
            {
                const int mt_w = (s >= 4) ? ((s-4) >> 2) : 3;
                const int g_w  = (s >= 4) ? ((s-4) & 3) : s;
                if (s >= 4 || chk > 0){
                    float* wp = gwB + 16*mt_w*516 + g_w;
                    wp[0*516] = p[s&3][0]; wp[1*516] = p[s&3][1];
                    wp[2*516] = p[s&3][2]; wp[3*516] = p[s&3][3];
                }
            }
            // 2. G_f MFMA for next chunk (reg-resident A — fills head bubble)
            p[s&3] = __builtin_amdgcn_mfma_f32_16x16x32_bf16(afg, bw[s&3][0], Z4, 0,0,0);

            // 3. h A-frags + gf read
            const unsigned short* hp = hist + ((s+15)&15)*576 + aoff;
            s16x8 h1 = *(const s16x8*)(hp +  0);
            s16x8 h2 = *(const s16x8*)(hp + 32);
            s16x8 h3 = *(const s16x8*)(hp + 64);
            s16x8 h4 = *(const s16x8*)(hp + 96);
            f32x4 gf = *(const f32x4*)(gfrB + s*4*516);

            // 4. prefetch next mt's A-frag
            if ((s & 3) == 3 && s < 15)
                afg = *(const s16x8*)(fch + (((s>>2)+1)*16 + lm)*32 + lg*8);

            // 5. 16 h-MFMAs (4 chains of 4)
            f32x4 a0 = __builtin_amdgcn_mfma_f32_16x16x32_bf16(h1, bw[0][1], Z4, 0,0,0);
            f32x4 a1 = __builtin_amdgcn_mfma_f32_16x16x32_bf16(h1, bw[1][1], Z4, 0,0,0);
            f32x4 a2 = __builtin_amdgcn_mfma_f32_16x16x32_bf16(h1, bw[2][1], Z4, 0,0,0);
            f32x4 a3 = __builtin_amdgcn_mfma_f32_16x16x32_bf16(h1, bw[3][1], Z4, 0,0,0);
            a0 = __builtin_amdgcn_mfma_f32_16x16x32_bf16(h2, bw[0][2], a0, 0,0,0);
            a1 = __builtin_amdgcn_mfma_f32_16x16x32_bf16(h2, bw[1][2], a1, 0,0,0);
            a2 = __builtin_amdgcn_mfma_f32_16x16x32_bf16(h2, bw[2][2], a2, 0,0,0);
            a3 = __builtin_amdgcn_mfma_f32_16x16x32_bf16(h2, bw[3][2], a3, 0,0,0);
            a0 = __builtin_amdgcn_mfma_f32_16x16x32_bf16(h3, bw[0][3], a0, 0,0,0);
            a1 = __builtin_amdgcn_mfma_f32_16x16x32_bf16(h3, bw[1][3], a1, 0,0,0);
            a2 = __builtin_amdgcn_mfma_f32_16x16x32_bf16(h3, bw[2][3], a2, 0,0,0);
            a3 = __builtin_amdgcn_mfma_f32_16x16x32_bf16(h3, bw[3][3], a3, 0,0,0);
            a0 = __builtin_amdgcn_mfma_f32_16x16x32_bf16(h4, bw[0][4], a0, 0,0,0);
            a1 = __builtin_amdgcn_mfma_f32_16x16x32_bf16(h4, bw[1][4], a1, 0,0,0);
            a2 = __builtin_amdgcn_mfma_f32_16x16x32_bf16(h4, bw[2][4], a2, 0,0,0);
            a3 = __builtin_amdgcn_mfma_f32_16x16x32_bf16(h4, bw[3][4], a3, 0,0,0);

            // 6. activations (gate pre-act = MFMA reg0 + G_f)
            float gi  = a0[0] + gf[0];
            float gfo = a1[0] + gf[1];
            float gg  = a2[0] + gf[2];
            float go  = a3[0] + gf[3];
            float si = frcp(1.f + fexp2(fmaf(gi,  -L2E, nLb0)));
            float sf = frcp(1.f + fexp2(fmaf(gfo, -L2E, nLb1)));
            float so = frcp(1.f + fexp2(fmaf(go,  -L2E, nLb3)));
            float eg = fexp2(fmaf(gg, 2.f*L2E, b2g));
            float tg_ = fmaf(-2.f, frcp(1.f + eg), 1.f);
            c = sf*c + si*tg_;
            float ec = fexp2(c * (2.f*L2E));
            float tc_ = fmaf(-2.f, frcp(1.f + ec), 1.f);
            float h = so * tc_;

            unsigned hp2;
            asm("v_cvt_pk_bf16_f32 %0, %1, %1" : "=v"(hp2) : "v"(h));
            hist[s*576 + hwoff] = (unsigned short)hp2;

            bar_lgkm();
        }
    }

    // final y window (chunk NCHK-1)
    if (w >= 4){
        const int mt = w - 4;
        const unsigned short* ap = hist + (mt*4 + (lm>>2))*576 + (lm&3)*144 + lg*8;
        s16x8 q0 = *(const s16x8*)(ap +  0);
        s16x8 q1 = *(const s16x8*)(ap + 32);
        s16x8 q2 = *(const s16x8*)(ap + 64);
        s16x8 q3 = *(const s16x8*)(ap + 96);
        f32x4 acc = __builtin_amdgcn_mfma_f32_16x16x32_bf16(q0, wlf[0], Z4, 0,0,0);
        acc = __builtin_amdgcn_mfma_f32_16x16x32_bf16(q1, wlf[1], acc, 0,0,0);
        acc = __builtin_amdgcn_mfma_f32_16x16x32_bf16(q2, wlf[2], acc, 0,0,0);
        acc = __builtin_amdgcn_mfma_f32_16x16x32_bf16(q3, wlf[3], acc, 0,0,0);
        if (lm < 2){
            const int tY = (T_ - 16) + mt*4 + lg;
            #pragma unroll
            for (int r = 0; r < 4; ++r)
                out[((long)(gb0 + r)*T_ + tY)*2 + lm] = acc[r] + blv;
        }
    }
}

extern "C" void kernel_launch(void* const* d_in, const int* in_sizes, int n_in,
                              void* d_out, int out_size, void* d_ws, size_t ws_size,
                              hipStream_t stream)
{
    const float* x     = (const float*)d_in[0];
    const float* u     = (const float*)d_in[1];
    const float* dtp   = (const float*)d_in[2];
    const float* theta = (const float*)d_in[3];
    const float* He    = (const float*)d_in[4];
    const float* taue  = (const float*)d_in[5];
    const float* Hi    = (const float*)d_in[6];
    const float* taui  = (const float*)d_in[7];
    const float* l1    = (const float*)d_in[8];
    const float* l2    = (const float*)d_in[9];
    const float* l3    = (const float*)d_in[10];
    const float* l4    = (const float*)d_in[11];
    const float* Cf    = (const float*)d_in[12];
    const float* Cl    = (const float*)d_in[13];
    const float* Cu    = (const float*)d_in[14];
    const float* Cb    = (const float*)d_in[15];
    const float* Wih   = (const float*)d_in[16];
    const float* Whh   = (const float*)d_in[17];
    const float* bih   = (const float*)d_in[18];
    const float* bhh   = (const float*)d_in[19];
    const float* Wlin  = (const float*)d_in[20];
    const float* blin  = (const float*)d_in[21];

    unsigned short* feats = (unsigned short*)d_ws;   // B*T*32 bf16 = 16 MiB (permuted)

    k_feats<<<(B_*T_)/256, 256, 0, stream>>>(x,u,dtp,theta,He,taue,Hi,taui,
                                             l1,l2,l3,l4,Cf,Cl,Cu,Cb,feats);
    k_scan<<<16, 512, 0, stream>>>(feats, Wih, Whh, bih, bhh, Wlin, blin, (float*)d_out);
}

// Round 8
// 1768.393 us; speedup vs baseline: 1.0915x; 1.0915x over previous
//
#include <hip/hip_runtime.h>

#define B_   64
#define T_   4096
#define HID_ 128

typedef float f32x4 __attribute__((ext_vector_type(4)));
typedef short s16x8 __attribute__((ext_vector_type(8)));
typedef short s16x4 __attribute__((ext_vector_type(4)));

__device__ __forceinline__ float fexp2(float x){ float r; asm("v_exp_f32 %0, %1":"=v"(r):"v"(x)); return r; }
__device__ __forceinline__ float frcp (float x){ float r; asm("v_rcp_f32 %0, %1":"=v"(r):"v"(x)); return r; }
__device__ __forceinline__ unsigned short f2bf(float f){
    unsigned u = __float_as_uint(f);
    u += 0x7FFFu + ((u >> 16) & 1u);      // round-to-nearest-even
    return (unsigned short)(u >> 16);
}
__device__ __forceinline__ float sigf(float x){
    return frcp(1.0f + fexp2(-1.44269504089f * x));
}
// barrier that drains LDS only (no vmcnt) — global prefetch/stores fly across steps
__device__ __forceinline__ void bar_lgkm(){
    asm volatile("s_waitcnt lgkmcnt(0)\ns_barrier" ::: "memory");
    __builtin_amdgcn_sched_barrier(0);
}

// ---------------- Phase 1: ODE features -> feats[B][T][32] bf16 (PERMUTED) ----
__global__ __launch_bounds__(256) void k_feats(
    const float* __restrict__ x, const float* __restrict__ u,
    const float* __restrict__ dtp, const float* __restrict__ theta,
    const float* __restrict__ He, const float* __restrict__ taue,
    const float* __restrict__ Hi, const float* __restrict__ taui,
    const float* __restrict__ l1, const float* __restrict__ l2,
    const float* __restrict__ l3, const float* __restrict__ l4,
    const float* __restrict__ Cf, const float* __restrict__ Cl,
    const float* __restrict__ Cu, const float* __restrict__ Cb,
    unsigned short* __restrict__ feats)
{
    long idx = (long)blockIdx.x * 256 + threadIdx.x;   // b*T + t
    const float dt = dtp[0];
    const float th00 = theta[0], th01 = theta[1], th10 = theta[2], th11 = theta[3];
    const float he = He[0], te = taue[0], hi = Hi[0], ti = taui[0];
    const float L1 = l1[0], L2v = l2[0], L3 = l3[0], L4 = l4[0];
    float cf[4], cl[4], cu[4], cb[4];
    #pragma unroll
    for (int i = 0; i < 4; ++i){ cf[i]=Cf[i]; cl[i]=Cl[i]; cu[i]=Cu[i]; cb[i]=Cb[i]; }
    const float ite  = 1.f/te, iti = 1.f/ti;
    const float He_te = he*ite, ite2 = ite*ite;
    const float Hi_ti = hi*iti, iti2 = iti*iti;

    float X[22];
    const float2* xr = (const float2*)(x + idx*22);
    #pragma unroll
    for (int i = 0; i < 11; ++i){ float2 v = xr[i]; X[2*i] = v.x; X[2*i+1] = v.y; }
    float2 uv = ((const float2*)u)[idx];

    float xt0 = X[0]*th00 + X[1]*th10;
    float xt1 = X[0]*th01 + X[1]*th11;
    float ut0 = uv.x*th00 + uv.y*th10;
    float ut1 = uv.x*th01 + uv.y*th11;
    float s0 = sigf(xt0), s1 = sigf(xt1);

    float Mf00 = cf[0]+cl[0]+L1, Mf01 = cf[1]+cl[1], Mf10 = cf[2]+cl[2], Mf11 = cf[3]+cl[3]+L1;
    float Af0 = Mf00*s0 + Mf01*s1, Af1 = Mf10*s0 + Mf11*s1;
    float Au0 = cu[0]*ut0 + cu[1]*ut1, Au1 = cu[2]*ut0 + cu[3]*ut1;
    float Mb00 = cb[0]+cl[0], Mb01 = cb[1]+cl[1], Mb10 = cb[2]+cl[2], Mb11 = cb[3]+cl[3];
    float Abl0 = Mb00*s0 + Mb01*s1, Abl1 = Mb10*s0 + Mb11*s1;
    float A30 = (Mb00+L3)*s0 + Mb01*s1,  A31 = Mb10*s0 + (Mb11+L3)*s1;

    float F[22];
    F[0]  = X[0]  + dt*(X[10]-X[12]);
    F[1]  = X[1]  + dt*(X[11]-X[13]);
    F[2]  = X[2]  + dt*X[8];
    F[3]  = X[3]  + dt*X[9];
    F[4]  = X[4]  + dt*X[10];
    F[5]  = X[5]  + dt*X[11];
    F[6]  = X[6]  + dt*X[12];
    F[7]  = X[7]  + dt*X[13];
    F[8]  = X[8]  + dt*(He_te*(Af0+Au0) - 2.f*X[8]*ite  - X[2]*ite2);
    F[9]  = X[9]  + dt*(He_te*(Af1+Au1) - 2.f*X[9]*ite  - X[3]*ite2);
    F[10] = X[10] + dt*(He_te*(Abl0 + L2v*sigf(X[6])) - 2.f*X[10]*ite - X[4]*ite2);
    F[11] = X[11] + dt*(He_te*(Abl1 + L2v*sigf(X[7])) - 2.f*X[11]*ite - X[5]*ite2);
    F[12] = X[12] + dt*(Hi_ti*L4*sigf(X[14]) - 2.f*X[12]*iti - X[6]*iti2);
    F[13] = X[13] + dt*(Hi_ti*L4*sigf(X[15]) - 2.f*X[13]*iti - X[7]*iti2);
    F[14] = X[14] + dt*X[16];
    F[15] = X[15] + dt*X[17];
    F[16] = X[16] + dt*(He_te*A30 - 2.f*X[16]*ite - X[14]*ite2);
    F[17] = X[17] + dt*(He_te*A31 - 2.f*X[17]*ite - X[15]*ite2);
    F[18] = X[18]; F[19] = X[19]; F[20] = X[20]; F[21] = X[21];

    unsigned short op[32];
    #pragma unroll
    for (int s = 0; s < 4; ++s){
        #pragma unroll
        for (int e = 0; e < 8; ++e){
            int j = s*4 + (e & 3) + ((e >> 2) << 4);
            op[s*8+e] = (j < 22) ? f2bf(F[j]) : (unsigned short)0;
        }
    }
    uint4* dst = (uint4*)(feats + idx*32);
    #pragma unroll
    for (int q = 0; q < 4; ++q){
        uint4 v;
        v.x = (unsigned)op[q*8+0] | ((unsigned)op[q*8+1] << 16);
        v.y = (unsigned)op[q*8+2] | ((unsigned)op[q*8+3] << 16);
        v.z = (unsigned)op[q*8+4] | ((unsigned)op[q*8+5] << 16);
        v.w = (unsigned)op[q*8+6] | ((unsigned)op[q*8+7] << 16);
        dst[q] = v;
    }
}

// ---------------- Phase 2: LSTM scan, G_f in registers ----------------
// 16 blocks x 4 batches, 8 waves; wave w owns j in [w*16, w*16+16).
// Chunk (16 steps) boundary:
//   (1) G_f burst: A-rows arranged (b = m>>2, t = 4mt + (m&3)) so the D frag
//       lands as p[mt][g][r] = G_f(t=4mt+r, b=lg, j=nj) — register-resident,
//       consumed directly by the act at step s = 4mt+r. No LDS, no conflicts.
//   (2) fch <- feats(chk+1); y-GEMM(chk-1) on waves 4-7; prefetch feats(chk+2).
// Step: 4 ds_read_b128 (h frags) + 16 MFMA + act(regs) + ds_write h + lgkm-bar.
__global__ __launch_bounds__(512, 1) void k_scan(
    const unsigned short* __restrict__ feats,
    const float* __restrict__ Wih, const float* __restrict__ Whh,
    const float* __restrict__ bih, const float* __restrict__ bhh,
    const float* __restrict__ Wlin, const float* __restrict__ blin,
    float* __restrict__ out)
{
    __shared__ __align__(16) unsigned short hist[16 * 576];   // 18.4 KB
    __shared__ __align__(16) unsigned short fch[64 * 32];     // 4 KB (feats, current chunk)

    const int tid = threadIdx.x;
    const int w  = tid >> 6;
    const int l  = tid & 63;
    const int lm = l & 15;
    const int lg = l >> 4;
    const int gb0 = blockIdx.x * 4;
    const int ar  = lm >> 2;

    for (int i = tid; i < 16*576/2; i += 512) ((unsigned*)hist)[i] = 0u;

    // ---- weight B-fragments (bf16) ----
    const int nj = w*16 + lm;
    s16x8 bw[4][5];
    #pragma unroll
    for (int t4 = 0; t4 < 4; ++t4){
        int n = t4*128 + nj;
        #pragma unroll
        for (int kc = 0; kc < 5; ++kc){
            #pragma unroll
            for (int j = 0; j < 8; ++j){
                int k = kc*32 + lg*4 + (j & 3) + ((j >> 2) << 4);
                float wv = 0.f;
                if (kc == 0){ if (k < 22) wv = Wih[n*22 + k]; }
                else        { wv = Whh[n*128 + (k - 32)]; }
                bw[t4][kc][j] = (short)f2bf(wv);
            }
        }
    }
    s16x8 wlf[4];
    #pragma unroll
    for (int kc = 0; kc < 4; ++kc){
        #pragma unroll
        for (int j = 0; j < 8; ++j){
            int k = kc*32 + lg*4 + (j & 3) + ((j >> 2) << 4);
            wlf[kc][j] = (lm < 2) ? (short)f2bf(Wlin[lm*128 + k]) : (short)0;
        }
    }
    const float blv = blin[l & 1];

    const float L2E = 1.44269504089f;
    float nLb0, nLb1, nLb3, b2g;
    {
        float bi = bih[0*128+nj] + bhh[0*128+nj];
        float bf = bih[1*128+nj] + bhh[1*128+nj];
        float bg = bih[2*128+nj] + bhh[2*128+nj];
        float bo = bih[3*128+nj] + bhh[3*128+nj];
        nLb0 = -L2E*bi; nLb1 = -L2E*bf; nLb3 = -L2E*bo; b2g = 2.f*L2E*bg;
    }

    // offsets
    const int aoff = ar*144 + lg*8;                   // h A-frag (shorts) within a hist slot
    const int khc = nj >> 5;
    const int hwoff = lg*144 + (khc*4 + ((nj >> 2) & 3))*8 + ((nj >> 4) & 1)*4 + (nj & 3);
    // G_f A-frag read: lane supplies A-row lm = (b=lm>>2, tt=lm&3) of M-tile mt
    const int gfoff = ((lm & 3)*4 + (lm >> 2))*32 + lg*8;   // + mt*16*32 shorts

    // feats staging: threads < 256 own one 16B unit of the 4KB chunk
    const int u_t = tid >> 4, u_b = (tid >> 2) & 3, u_q = tid & 3;
    const unsigned short* psrc = feats + ((long)(gb0 + u_b)*T_ + u_t)*32 + u_q*8;
    unsigned short* const pdst = fch + (u_t*4 + u_b)*32 + u_q*8;

    const f32x4 Z4 = {0.f, 0.f, 0.f, 0.f};

    // ---- prologue: fch = feats(chunk 0); pend = feats(chunk 1) ----
    if (tid < 256){ uint4 t0 = *(const uint4*)psrc; *(uint4*)pdst = t0; }
    uint4 pend = {0,0,0,0};
    if (tid < 256) pend = *(const uint4*)(psrc + (long)16*32);
    __syncthreads();

    f32x4 p[4][4];                     // p[mt][g] : G_f(t=4mt+r, b=lg, j=nj, gate g)
    float c = 0.f;
    const int NCHK = T_/16;

    for (int chk = 0; chk < NCHK; ++chk){
        // ---- (1) G_f burst for THIS chunk (fch holds feats(chk)) ----
        #pragma unroll
        for (int mt = 0; mt < 4; ++mt){
            s16x8 af = *(const s16x8*)(fch + mt*16*32 + gfoff);
            p[mt][0] = __builtin_amdgcn_mfma_f32_16x16x32_bf16(af, bw[0][0], Z4, 0,0,0);
            p[mt][1] = __builtin_amdgcn_mfma_f32_16x16x32_bf16(af, bw[1][0], Z4, 0,0,0);
            p[mt][2] = __builtin_amdgcn_mfma_f32_16x16x32_bf16(af, bw[2][0], Z4, 0,0,0);
            p[mt][3] = __builtin_amdgcn_mfma_f32_16x16x32_bf16(af, bw[3][0], Z4, 0,0,0);
        }
        bar_lgkm();                                    // fch reads done (all waves)

        // ---- (2) fch <- feats(chk+1); prefetch feats(chk+2); y(chk-1) ----
        if (tid < 256){
            *(uint4*)pdst = pend;
            long nk = (chk < NCHK-2) ? (chk + 2) : (NCHK-1);
            pend = *(const uint4*)(psrc + nk*16*32);
        }
        if (w >= 4 && chk > 0){
            const int mt = w - 4;
            const unsigned short* ap = hist + (mt*4 + (lm>>2))*576 + (lm&3)*144 + lg*8;
            s16x8 q0 = *(const s16x8*)(ap +  0);
            s16x8 q1 = *(const s16x8*)(ap + 32);
            s16x8 q2 = *(const s16x8*)(ap + 64);
            s16x8 q3 = *(const s16x8*)(ap + 96);
            f32x4 acc = __builtin_amdgcn_mfma_f32_16x16x32_bf16(q0, wlf[0], Z4, 0,0,0);
            acc = __builtin_amdgcn_mfma_f32_16x16x32_bf16(q1, wlf[1], acc, 0,0,0);
            acc = __builtin_amdgcn_mfma_f32_16x16x32_bf16(q2, wlf[2], acc, 0,0,0);
            acc = __builtin_amdgcn_mfma_f32_16x16x32_bf16(q3, wlf[3], acc, 0,0,0);
            if (lm < 2){
                const int tY = (chk - 1)*16 + mt*4 + lg;
                #pragma unroll
                for (int r = 0; r < 4; ++r)
                    out[((long)(gb0 + r)*T_ + tY)*2 + lm] = acc[r] + blv;
            }
        }
        bar_lgkm();                                    // fch stored; y hist reads done

        // ---- 16 steps, fully unrolled ----
        #pragma unroll
        for (int s = 0; s < 16; ++s){
            const unsigned short* hp = hist + ((s+15)&15)*576 + aoff;
            s16x8 h1 = *(const s16x8*)(hp +  0);
            s16x8 h2 = *(const s16x8*)(hp + 32);
            s16x8 h3 = *(const s16x8*)(hp + 64);
            s16x8 h4 = *(const s16x8*)(hp + 96);

            f32x4 a0 = __builtin_amdgcn_mfma_f32_16x16x32_bf16(h1, bw[0][1], Z4, 0,0,0);
            f32x4 a1 = __builtin_amdgcn_mfma_f32_16x16x32_bf16(h1, bw[1][1], Z4, 0,0,0);
            f32x4 a2 = __builtin_amdgcn_mfma_f32_16x16x32_bf16(h1, bw[2][1], Z4, 0,0,0);
            f32x4 a3 = __builtin_amdgcn_mfma_f32_16x16x32_bf16(h1, bw[3][1], Z4, 0,0,0);
            a0 = __builtin_amdgcn_mfma_f32_16x16x32_bf16(h2, bw[0][2], a0, 0,0,0);
            a1 = __builtin_amdgcn_mfma_f32_16x16x32_bf16(h2, bw[1][2], a1, 0,0,0);
            a2 = __builtin_amdgcn_mfma_f32_16x16x32_bf16(h2, bw[2][2], a2, 0,0,0);
            a3 = __builtin_amdgcn_mfma_f32_16x16x32_bf16(h2, bw[3][2], a3, 0,0,0);
            a0 = __builtin_amdgcn_mfma_f32_16x16x32_bf16(h3, bw[0][3], a0, 0,0,0);
            a1 = __builtin_amdgcn_mfma_f32_16x16x32_bf16(h3, bw[1][3], a1, 0,0,0);
            a2 = __builtin_amdgcn_mfma_f32_16x16x32_bf16(h3, bw[2][3], a2, 0,0,0);
            a3 = __builtin_amdgcn_mfma_f32_16x16x32_bf16(h3, bw[3][3], a3, 0,0,0);
            a0 = __builtin_amdgcn_mfma_f32_16x16x32_bf16(h4, bw[0][4], a0, 0,0,0);
            a1 = __builtin_amdgcn_mfma_f32_16x16x32_bf16(h4, bw[1][4], a1, 0,0,0);
            a2 = __builtin_amdgcn_mfma_f32_16x16x32_bf16(h4, bw[2][4], a2, 0,0,0);
            a3 = __builtin_amdgcn_mfma_f32_16x16x32_bf16(h4, bw[3][4], a3, 0,0,0);

            // act: gate pre-act = MFMA reg0 + register G_f
            float gi  = a0[0] + p[s>>2][0][s&3];
            float gfo = a1[0] + p[s>>2][1][s&3];
            float gg  = a2[0] + p[s>>2][2][s&3];
            float go  = a3[0] + p[s>>2][3][s&3];
            float si = frcp(1.f + fexp2(fmaf(gi,  -L2E, nLb0)));
            float sf = frcp(1.f + fexp2(fmaf(gfo, -L2E, nLb1)));
            float so = frcp(1.f + fexp2(fmaf(go,  -L2E, nLb3)));
            float eg = fexp2(fmaf(gg, 2.f*L2E, b2g));
            float tg_ = fmaf(-2.f, frcp(1.f + eg), 1.f);
            c = sf*c + si*tg_;
            float ec = fexp2(c * (2.f*L2E));
            float tc_ = fmaf(-2.f, frcp(1.f + ec), 1.f);
            float h = so * tc_;

            unsigned hp2;
            asm("v_cvt_pk_bf16_f32 %0, %1, %1" : "=v"(hp2) : "v"(h));
            hist[s*576 + hwoff] = (unsigned short)hp2;

            bar_lgkm();
        }
    }

    // final y window (chunk NCHK-1)
    if (w >= 4){
        const int mt = w - 4;
        const unsigned short* ap = hist + (mt*4 + (lm>>2))*576 + (lm&3)*144 + lg*8;
        s16x8 q0 = *(const s16x8*)(ap +  0);
        s16x8 q1 = *(const s16x8*)(ap + 32);
        s16x8 q2 = *(const s16x8*)(ap + 64);
        s16x8 q3 = *(const s16x8*)(ap + 96);
        f32x4 acc = __builtin_amdgcn_mfma_f32_16x16x32_bf16(q0, wlf[0], Z4, 0,0,0);
        acc = __builtin_amdgcn_mfma_f32_16x16x32_bf16(q1, wlf[1], acc, 0,0,0);
        acc = __builtin_amdgcn_mfma_f32_16x16x32_bf16(q2, wlf[2], acc, 0,0,0);
        acc = __builtin_amdgcn_mfma_f32_16x16x32_bf16(q3, wlf[3], acc, 0,0,0);
        if (lm < 2){
            const int tY = (T_ - 16) + mt*4 + lg;
            #pragma unroll
            for (int r = 0; r < 4; ++r)
                out[((long)(gb0 + r)*T_ + tY)*2 + lm] = acc[r] + blv;
        }
    }
}

extern "C" void kernel_launch(void* const* d_in, const int* in_sizes, int n_in,
                              void* d_out, int out_size, void* d_ws, size_t ws_size,
                              hipStream_t stream)
{
    const float* x     = (const float*)d_in[0];
    const float* u     = (const float*)d_in[1];
    const float* dtp   = (const float*)d_in[2];
    const float* theta = (const float*)d_in[3];
    const float* He    = (const float*)d_in[4];
    const float* taue  = (const float*)d_in[5];
    const float* Hi    = (const float*)d_in[6];
    const float* taui  = (const float*)d_in[7];
    const float* l1    = (const float*)d_in[8];
    const float* l2    = (const float*)d_in[9];
    const float* l3    = (const float*)d_in[10];
    const float* l4    = (const float*)d_in[11];
    const float* Cf    = (const float*)d_in[12];
    const float* Cl    = (const float*)d_in[13];
    const float* Cu    = (const float*)d_in[14];
    const float* Cb    = (const float*)d_in[15];
    const float* Wih   = (const float*)d_in[16];
    const float* Whh   = (const float*)d_in[17];
    const float* bih   = (const float*)d_in[18];
    const float* bhh   = (const float*)d_in[19];
    const float* Wlin  = (const float*)d_in[20];
    const float* blin  = (const float*)d_in[21];

    unsigned short* feats = (unsigned short*)d_ws;   // B*T*32 bf16 = 16 MiB (permuted)

    k_feats<<<(B_*T_)/256, 256, 0, stream>>>(x,u,dtp,theta,He,taue,Hi,taui,
                                             l1,l2,l3,l4,Cf,Cl,Cu,Cb,feats);
    k_scan<<<16, 512, 0, stream>>>(feats, Wih, Whh, bih, bhh, Wlin, blin, (float*)d_out);
}

// Round 9
// 1666.371 us; speedup vs baseline: 1.1583x; 1.0612x over previous
//
#include <hip/hip_runtime.h>

#define B_   64
#define T_   4096
#define HID_ 128

typedef float f32x4 __attribute__((ext_vector_type(4)));
typedef short s16x8 __attribute__((ext_vector_type(8)));
typedef short s16x4 __attribute__((ext_vector_type(4)));

__device__ __forceinline__ float fexp2(float x){ float r; asm("v_exp_f32 %0, %1":"=v"(r):"v"(x)); return r; }
__device__ __forceinline__ float frcp (float x){ float r; asm("v_rcp_f32 %0, %1":"=v"(r):"v"(x)); return r; }
__device__ __forceinline__ unsigned short f2bf(float f){
    unsigned u = __float_as_uint(f);
    u += 0x7FFFu + ((u >> 16) & 1u);      // round-to-nearest-even
    return (unsigned short)(u >> 16);
}
__device__ __forceinline__ float sigf(float x){
    return frcp(1.0f + fexp2(-1.44269504089f * x));
}
// barrier that drains LDS only (no vmcnt) — global prefetch/stores fly across steps
__device__ __forceinline__ void bar_lgkm(){
    asm volatile("s_waitcnt lgkmcnt(0)\ns_barrier" ::: "memory");
    __builtin_amdgcn_sched_barrier(0);
}

// ---------------- Phase 1: ODE features -> feats[B][T][32] bf16 (PERMUTED) ----
__global__ __launch_bounds__(256) void k_feats(
    const float* __restrict__ x, const float* __restrict__ u,
    const float* __restrict__ dtp, const float* __restrict__ theta,
    const float* __restrict__ He, const float* __restrict__ taue,
    const float* __restrict__ Hi, const float* __restrict__ taui,
    const float* __restrict__ l1, const float* __restrict__ l2,
    const float* __restrict__ l3, const float* __restrict__ l4,
    const float* __restrict__ Cf, const float* __restrict__ Cl,
    const float* __restrict__ Cu, const float* __restrict__ Cb,
    unsigned short* __restrict__ feats)
{
    long idx = (long)blockIdx.x * 256 + threadIdx.x;   // b*T + t
    const float dt = dtp[0];
    const float th00 = theta[0], th01 = theta[1], th10 = theta[2], th11 = theta[3];
    const float he = He[0], te = taue[0], hi = Hi[0], ti = taui[0];
    const float L1 = l1[0], L2v = l2[0], L3 = l3[0], L4 = l4[0];
    float cf[4], cl[4], cu[4], cb[4];
    #pragma unroll
    for (int i = 0; i < 4; ++i){ cf[i]=Cf[i]; cl[i]=Cl[i]; cu[i]=Cu[i]; cb[i]=Cb[i]; }
    const float ite  = 1.f/te, iti = 1.f/ti;
    const float He_te = he*ite, ite2 = ite*ite;
    const float Hi_ti = hi*iti, iti2 = iti*iti;

    float X[22];
    const float2* xr = (const float2*)(x + idx*22);
    #pragma unroll
    for (int i = 0; i < 11; ++i){ float2 v = xr[i]; X[2*i] = v.x; X[2*i+1] = v.y; }
    float2 uv = ((const float2*)u)[idx];

    float xt0 = X[0]*th00 + X[1]*th10;
    float xt1 = X[0]*th01 + X[1]*th11;
    float ut0 = uv.x*th00 + uv.y*th10;
    float ut1 = uv.x*th01 + uv.y*th11;
    float s0 = sigf(xt0), s1 = sigf(xt1);

    float Mf00 = cf[0]+cl[0]+L1, Mf01 = cf[1]+cl[1], Mf10 = cf[2]+cl[2], Mf11 = cf[3]+cl[3]+L1;
    float Af0 = Mf00*s0 + Mf01*s1, Af1 = Mf10*s0 + Mf11*s1;
    float Au0 = cu[0]*ut0 + cu[1]*ut1, Au1 = cu[2]*ut0 + cu[3]*ut1;
    float Mb00 = cb[0]+cl[0], Mb01 = cb[1]+cl[1], Mb10 = cb[2]+cl[2], Mb11 = cb[3]+cl[3];
    float Abl0 = Mb00*s0 + Mb01*s1, Abl1 = Mb10*s0 + Mb11*s1;
    float A30 = (Mb00+L3)*s0 + Mb01*s1,  A31 = Mb10*s0 + (Mb11+L3)*s1;

    float F[22];
    F[0]  = X[0]  + dt*(X[10]-X[12]);
    F[1]  = X[1]  + dt*(X[11]-X[13]);
    F[2]  = X[2]  + dt*X[8];
    F[3]  = X[3]  + dt*X[9];
    F[4]  = X[4]  + dt*X[10];
    F[5]  = X[5]  + dt*X[11];
    F[6]  = X[6]  + dt*X[12];
    F[7]  = X[7]  + dt*X[13];
    F[8]  = X[8]  + dt*(He_te*(Af0+Au0) - 2.f*X[8]*ite  - X[2]*ite2);
    F[9]  = X[9]  + dt*(He_te*(Af1+Au1) - 2.f*X[9]*ite  - X[3]*ite2);
    F[10] = X[10] + dt*(He_te*(Abl0 + L2v*sigf(X[6])) - 2.f*X[10]*ite - X[4]*ite2);
    F[11] = X[11] + dt*(He_te*(Abl1 + L2v*sigf(X[7])) - 2.f*X[11]*ite - X[5]*ite2);
    F[12] = X[12] + dt*(Hi_ti*L4*sigf(X[14]) - 2.f*X[12]*iti - X[6]*iti2);
    F[13] = X[13] + dt*(Hi_ti*L4*sigf(X[15]) - 2.f*X[13]*iti - X[7]*iti2);
    F[14] = X[14] + dt*X[16];
    F[15] = X[15] + dt*X[17];
    F[16] = X[16] + dt*(He_te*A30 - 2.f*X[16]*ite - X[14]*ite2);
    F[17] = X[17] + dt*(He_te*A31 - 2.f*X[17]*ite - X[15]*ite2);
    F[18] = X[18]; F[19] = X[19]; F[20] = X[20]; F[21] = X[21];

    unsigned short op[32];
    #pragma unroll
    for (int s = 0; s < 4; ++s){
        #pragma unroll
        for (int e = 0; e < 8; ++e){
            int j = s*4 + (e & 3) + ((e >> 2) << 4);
            op[s*8+e] = (j < 22) ? f2bf(F[j]) : (unsigned short)0;
        }
    }
    uint4* dst = (uint4*)(feats + idx*32);
    #pragma unroll
    for (int q = 0; q < 4; ++q){
        uint4 v;
        v.x = (unsigned)op[q*8+0] | ((unsigned)op[q*8+1] << 16);
        v.y = (unsigned)op[q*8+2] | ((unsigned)op[q*8+3] << 16);
        v.z = (unsigned)op[q*8+4] | ((unsigned)op[q*8+5] << 16);
        v.w = (unsigned)op[q*8+6] | ((unsigned)op[q*8+7] << 16);
        dst[q] = v;
    }
}

// ---------------- Phase 2: LSTM scan, G_f diluted 1 MFMA/step ----------------
// 16 blocks x 4 batches, 8 waves; wave w owns j in [w*16, w*16+16).
// Invariant at chunk chk: P = G_f(chk) in regs; pend regs = feats(chk+1).
// Boundary: fch <- pend; y-GEMM(chk-1); issue pend = feats(chk+2); 1 barrier.
// Step s: h ds_reads; [afg read every 4th step]; 1 G_f MFMA -> PN[s>>2][s&3]
// (fills the ds-latency window); 16 h-MFMAs; act (gate = MFMA + P); h write; bar.
__global__ __launch_bounds__(512, 1) void k_scan(
    const unsigned short* __restrict__ feats,
    const float* __restrict__ Wih, const float* __restrict__ Whh,
    const float* __restrict__ bih, const float* __restrict__ bhh,
    const float* __restrict__ Wlin, const float* __restrict__ blin,
    float* __restrict__ out)
{
    __shared__ __align__(16) unsigned short hist[16 * 576];   // 18.4 KB
    __shared__ __align__(16) unsigned short fch[64 * 32];     // 4 KB (feats of chk+1)

    const int tid = threadIdx.x;
    const int w  = tid >> 6;
    const int l  = tid & 63;
    const int lm = l & 15;
    const int lg = l >> 4;
    const int gb0 = blockIdx.x * 4;
    const int ar  = lm >> 2;

    for (int i = tid; i < 16*576/2; i += 512) ((unsigned*)hist)[i] = 0u;

    // ---- weight B-fragments (bf16) ----
    const int nj = w*16 + lm;
    s16x8 bw[4][5];
    #pragma unroll
    for (int t4 = 0; t4 < 4; ++t4){
        int n = t4*128 + nj;
        #pragma unroll
        for (int kc = 0; kc < 5; ++kc){
            #pragma unroll
            for (int j = 0; j < 8; ++j){
                int k = kc*32 + lg*4 + (j & 3) + ((j >> 2) << 4);
                float wv = 0.f;
                if (kc == 0){ if (k < 22) wv = Wih[n*22 + k]; }
                else        { wv = Whh[n*128 + (k - 32)]; }
                bw[t4][kc][j] = (short)f2bf(wv);
            }
        }
    }
    s16x8 wlf[4];
    #pragma unroll
    for (int kc = 0; kc < 4; ++kc){
        #pragma unroll
        for (int j = 0; j < 8; ++j){
            int k = kc*32 + lg*4 + (j & 3) + ((j >> 2) << 4);
            wlf[kc][j] = (lm < 2) ? (short)f2bf(Wlin[lm*128 + k]) : (short)0;
        }
    }
    const float blv = blin[l & 1];

    const float L2E = 1.44269504089f;
    float nLb0, nLb1, nLb3, b2g;
    {
        float bi = bih[0*128+nj] + bhh[0*128+nj];
        float bf = bih[1*128+nj] + bhh[1*128+nj];
        float bg = bih[2*128+nj] + bhh[2*128+nj];
        float bo = bih[3*128+nj] + bhh[3*128+nj];
        nLb0 = -L2E*bi; nLb1 = -L2E*bf; nLb3 = -L2E*bo; b2g = 2.f*L2E*bg;
    }

    // offsets
    const int aoff = ar*144 + lg*8;                   // h A-frag (shorts) within a hist slot
    const int khc = nj >> 5;
    const int hwoff = lg*144 + (khc*4 + ((nj >> 2) & 3))*8 + ((nj >> 4) & 1)*4 + (nj & 3);
    const int gfoff = ((lm & 3)*4 + (lm >> 2))*32 + lg*8;   // G_f A-frag; + mt*512 shorts

    // feats staging: threads < 256 own one 16B unit of the 4KB chunk
    const int u_t = tid >> 4, u_b = (tid >> 2) & 3, u_q = tid & 3;
    const unsigned short* psrc = feats + ((long)(gb0 + u_b)*T_ + u_t)*32 + u_q*8;
    unsigned short* const pdst = fch + (u_t*4 + u_b)*32 + u_q*8;

    const f32x4 Z4 = {0.f, 0.f, 0.f, 0.f};
    const int NCHK = T_/16;

    // ---- prologue: fch = feats(0); burst P = G_f(0); pend = feats(1) ----
    if (tid < 256){ uint4 t0 = *(const uint4*)psrc; *(uint4*)pdst = t0; }
    __syncthreads();
    f32x4 pA[4][4], pB[4][4];
    #pragma unroll
    for (int mt = 0; mt < 4; ++mt){
        s16x8 af = *(const s16x8*)(fch + mt*512 + gfoff);
        pA[mt][0] = __builtin_amdgcn_mfma_f32_16x16x32_bf16(af, bw[0][0], Z4, 0,0,0);
        pA[mt][1] = __builtin_amdgcn_mfma_f32_16x16x32_bf16(af, bw[1][0], Z4, 0,0,0);
        pA[mt][2] = __builtin_amdgcn_mfma_f32_16x16x32_bf16(af, bw[2][0], Z4, 0,0,0);
        pA[mt][3] = __builtin_amdgcn_mfma_f32_16x16x32_bf16(af, bw[3][0], Z4, 0,0,0);
    }
    uint4 pend = {0,0,0,0};
    if (tid < 256) pend = *(const uint4*)(psrc + (long)16*32);     // feats(1)
    __syncthreads();

    float c = 0.f;

    // boundary of chunk chk: fch <- pend (feats(chk+1)); y(chk-1); reissue pend
    auto boundary = [&](int chk){
        if (tid < 256) *(uint4*)pdst = pend;
        if (w >= 4 && chk > 0){
            const int mt = w - 4;
            const unsigned short* ap = hist + (mt*4 + (lm>>2))*576 + (lm&3)*144 + lg*8;
            s16x8 q0 = *(const s16x8*)(ap +  0);
            s16x8 q1 = *(const s16x8*)(ap + 32);
            s16x8 q2 = *(const s16x8*)(ap + 64);
            s16x8 q3 = *(const s16x8*)(ap + 96);
            f32x4 acc = __builtin_amdgcn_mfma_f32_16x16x32_bf16(q0, wlf[0], Z4, 0,0,0);
            acc = __builtin_amdgcn_mfma_f32_16x16x32_bf16(q1, wlf[1], acc, 0,0,0);
            acc = __builtin_amdgcn_mfma_f32_16x16x32_bf16(q2, wlf[2], acc, 0,0,0);
            acc = __builtin_amdgcn_mfma_f32_16x16x32_bf16(q3, wlf[3], acc, 0,0,0);
            if (lm < 2){
                const int tY = (chk - 1)*16 + mt*4 + lg;
                #pragma unroll
                for (int r = 0; r < 4; ++r)
                    out[((long)(gb0 + r)*T_ + tY)*2 + lm] = acc[r] + blv;
            }
        }
        {
            long nk = (chk < NCHK-2) ? (chk + 2) : (NCHK-1);
            if (tid < 256) pend = *(const uint4*)(psrc + nk*(long)(16*32));
        }
        bar_lgkm();
    };

    // 16 steps of one chunk: consume P, build PN = G_f(chk+1)
    auto steps = [&](f32x4 (&P)[4][4], f32x4 (&PN)[4][4]){
        s16x8 afg;
        #pragma unroll
        for (int s = 0; s < 16; ++s){
            const unsigned short* hp = hist + ((s+15)&15)*576 + aoff;
            s16x8 h1 = *(const s16x8*)(hp +  0);
            s16x8 h2 = *(const s16x8*)(hp + 32);
            s16x8 h3 = *(const s16x8*)(hp + 64);
            s16x8 h4 = *(const s16x8*)(hp + 96);
            if ((s & 3) == 0) afg = *(const s16x8*)(fch + (s>>2)*512 + gfoff);
            // fill the ds-latency window with the G_f MFMA for next chunk
            PN[s>>2][s&3] = __builtin_amdgcn_mfma_f32_16x16x32_bf16(afg, bw[s&3][0], Z4, 0,0,0);
            __builtin_amdgcn_sched_barrier(0);

            f32x4 a0 = __builtin_amdgcn_mfma_f32_16x16x32_bf16(h1, bw[0][1], Z4, 0,0,0);
            f32x4 a1 = __builtin_amdgcn_mfma_f32_16x16x32_bf16(h1, bw[1][1], Z4, 0,0,0);
            f32x4 a2 = __builtin_amdgcn_mfma_f32_16x16x32_bf16(h1, bw[2][1], Z4, 0,0,0);
            f32x4 a3 = __builtin_amdgcn_mfma_f32_16x16x32_bf16(h1, bw[3][1], Z4, 0,0,0);
            a0 = __builtin_amdgcn_mfma_f32_16x16x32_bf16(h2, bw[0][2], a0, 0,0,0);
            a1 = __builtin_amdgcn_mfma_f32_16x16x32_bf16(h2, bw[1][2], a1, 0,0,0);
            a2 = __builtin_amdgcn_mfma_f32_16x16x32_bf16(h2, bw[2][2], a2, 0,0,0);
            a3 = __builtin_amdgcn_mfma_f32_16x16x32_bf16(h2, bw[3][2], a3, 0,0,0);
            a0 = __builtin_amdgcn_mfma_f32_16x16x32_bf16(h3, bw[0][3], a0, 0,0,0);
            a1 = __builtin_amdgcn_mfma_f32_16x16x32_bf16(h3, bw[1][3], a1, 0,0,0);
            a2 = __builtin_amdgcn_mfma_f32_16x16x32_bf16(h3, bw[2][3], a2, 0,0,0);
            a3 = __builtin_amdgcn_mfma_f32_16x16x32_bf16(h3, bw[3][3], a3, 0,0,0);
            a0 = __builtin_amdgcn_mfma_f32_16x16x32_bf16(h4, bw[0][4], a0, 0,0,0);
            a1 = __builtin_amdgcn_mfma_f32_16x16x32_bf16(h4, bw[1][4], a1, 0,0,0);
            a2 = __builtin_amdgcn_mfma_f32_16x16x32_bf16(h4, bw[2][4], a2, 0,0,0);
            a3 = __builtin_amdgcn_mfma_f32_16x16x32_bf16(h4, bw[3][4], a3, 0,0,0);

            float gi  = a0[0] + P[s>>2][0][s&3];
            float gfo = a1[0] + P[s>>2][1][s&3];
            float gg  = a2[0] + P[s>>2][2][s&3];
            float go  = a3[0] + P[s>>2][3][s&3];
            float si = frcp(1.f + fexp2(fmaf(gi,  -L2E, nLb0)));
            float sf = frcp(1.f + fexp2(fmaf(gfo, -L2E, nLb1)));
            float so = frcp(1.f + fexp2(fmaf(go,  -L2E, nLb3)));
            float eg = fexp2(fmaf(gg, 2.f*L2E, b2g));
            float tg_ = fmaf(-2.f, frcp(1.f + eg), 1.f);
            c = sf*c + si*tg_;
            float ec = fexp2(c * (2.f*L2E));
            float tc_ = fmaf(-2.f, frcp(1.f + ec), 1.f);
            float h = so * tc_;

            unsigned hp2;
            asm("v_cvt_pk_bf16_f32 %0, %1, %1" : "=v"(hp2) : "v"(h));
            hist[s*576 + hwoff] = (unsigned short)hp2;

            bar_lgkm();
        }
    };

    for (int c2 = 0; c2 < NCHK/2; ++c2){
        boundary(2*c2);       steps(pA, pB);
        boundary(2*c2 + 1);   steps(pB, pA);
    }

    // final y window (chunk NCHK-1) — hist intact after last step barrier
    if (w >= 4){
        const int mt = w - 4;
        const unsigned short* ap = hist + (mt*4 + (lm>>2))*576 + (lm&3)*144 + lg*8;
        s16x8 q0 = *(const s16x8*)(ap +  0);
        s16x8 q1 = *(const s16x8*)(ap + 32);
        s16x8 q2 = *(const s16x8*)(ap + 64);
        s16x8 q3 = *(const s16x8*)(ap + 96);
        f32x4 acc = __builtin_amdgcn_mfma_f32_16x16x32_bf16(q0, wlf[0], Z4, 0,0,0);
        acc = __builtin_amdgcn_mfma_f32_16x16x32_bf16(q1, wlf[1], acc, 0,0,0);
        acc = __builtin_amdgcn_mfma_f32_16x16x32_bf16(q2, wlf[2], acc, 0,0,0);
        acc = __builtin_amdgcn_mfma_f32_16x16x32_bf16(q3, wlf[3], acc, 0,0,0);
        if (lm < 2){
            const int tY = (T_ - 16) + mt*4 + lg;
            #pragma unroll
            for (int r = 0; r < 4; ++r)
                out[((long)(gb0 + r)*T_ + tY)*2 + lm] = acc[r] + blv;
        }
    }
}

extern "C" void kernel_launch(void* const* d_in, const int* in_sizes, int n_in,
                              void* d_out, int out_size, void* d_ws, size_t ws_size,
                              hipStream_t stream)
{
    const float* x     = (const float*)d_in[0];
    const float* u     = (const float*)d_in[1];
    const float* dtp   = (const float*)d_in[2];
    const float* theta = (const float*)d_in[3];
    const float* He    = (const float*)d_in[4];
    const float* taue  = (const float*)d_in[5];
    const float* Hi    = (const float*)d_in[6];
    const float* taui  = (const float*)d_in[7];
    const float* l1    = (const float*)d_in[8];
    const float* l2    = (const float*)d_in[9];
    const float* l3    = (const float*)d_in[10];
    const float* l4    = (const float*)d_in[11];
    const float* Cf    = (const float*)d_in[12];
    const float* Cl    = (const float*)d_in[13];
    const float* Cu    = (const float*)d_in[14];
    const float* Cb    = (const float*)d_in[15];
    const float* Wih   = (const float*)d_in[16];
    const float* Whh   = (const float*)d_in[17];
    const float* bih   = (const float*)d_in[18];
    const float* bhh   = (const float*)d_in[19];
    const float* Wlin  = (const float*)d_in[20];
    const float* blin  = (const float*)d_in[21];

    unsigned short* feats = (unsigned short*)d_ws;   // B*T*32 bf16 = 16 MiB (permuted)

    k_feats<<<(B_*T_)/256, 256, 0, stream>>>(x,u,dtp,theta,He,taue,Hi,taui,
                                             l1,l2,l3,l4,Cf,Cl,Cu,Cb,feats);
    k_scan<<<16, 512, 0, stream>>>(feats, Wih, Whh, bih, bhh, Wlin, blin, (float*)d_out);
}

// Round 11
// 1654.185 us; speedup vs baseline: 1.1669x; 1.0074x over previous
//
#include <hip/hip_runtime.h>

#define B_   64
#define T_   4096
#define HID_ 128

typedef float f32x4 __attribute__((ext_vector_type(4)));
typedef short s16x8 __attribute__((ext_vector_type(8)));
typedef short s16x4 __attribute__((ext_vector_type(4)));

#if __has_builtin(__builtin_amdgcn_exp2f)
__device__ __forceinline__ float fexp2(float x){ return __builtin_amdgcn_exp2f(x); }
#else
__device__ __forceinline__ float fexp2(float x){ float r; asm("v_exp_f32 %0, %1":"=v"(r):"v"(x)); return r; }
#endif
#if __has_builtin(__builtin_amdgcn_rcpf)
__device__ __forceinline__ float frcp(float x){ return __builtin_amdgcn_rcpf(x); }
#else
__device__ __forceinline__ float frcp(float x){ float r; asm("v_rcp_f32 %0, %1":"=v"(r):"v"(x)); return r; }
#endif
__device__ __forceinline__ unsigned short f2bf(float f){
    unsigned u = __float_as_uint(f);
    u += 0x7FFFu + ((u >> 16) & 1u);      // round-to-nearest-even
    return (unsigned short)(u >> 16);
}
__device__ __forceinline__ float sigf(float x){
    return frcp(1.0f + fexp2(-1.44269504089f * x));
}
// barrier that drains LDS only (no vmcnt) — global prefetch/stores fly across steps
__device__ __forceinline__ void bar_lgkm(){
    asm volatile("s_waitcnt lgkmcnt(0)\ns_barrier" ::: "memory");
    __builtin_amdgcn_sched_barrier(0);
}

// ---------------- Phase 1: ODE features -> feats[B][T][32] bf16 (PERMUTED) ----
__global__ __launch_bounds__(256) void k_feats(
    const float* __restrict__ x, const float* __restrict__ u,
    const float* __restrict__ dtp, const float* __restrict__ theta,
    const float* __restrict__ He, const float* __restrict__ taue,
    const float* __restrict__ Hi, const float* __restrict__ taui,
    const float* __restrict__ l1, const float* __restrict__ l2,
    const float* __restrict__ l3, const float* __restrict__ l4,
    const float* __restrict__ Cf, const float* __restrict__ Cl,
    const float* __restrict__ Cu, const float* __restrict__ Cb,
    unsigned short* __restrict__ feats)
{
    long idx = (long)blockIdx.x * 256 + threadIdx.x;   // b*T + t
    const float dt = dtp[0];
    const float th00 = theta[0], th01 = theta[1], th10 = theta[2], th11 = theta[3];
    const float he = He[0], te = taue[0], hi = Hi[0], ti = taui[0];
    const float L1 = l1[0], L2v = l2[0], L3 = l3[0], L4 = l4[0];
    float cf[4], cl[4], cu[4], cb[4];
    #pragma unroll
    for (int i = 0; i < 4; ++i){ cf[i]=Cf[i]; cl[i]=Cl[i]; cu[i]=Cu[i]; cb[i]=Cb[i]; }
    const float ite  = 1.f/te, iti = 1.f/ti;
    const float He_te = he*ite, ite2 = ite*ite;
    const float Hi_ti = hi*iti, iti2 = iti*iti;

    float X[22];
    const float2* xr = (const float2*)(x + idx*22);
    #pragma unroll
    for (int i = 0; i < 11; ++i){ float2 v = xr[i]; X[2*i] = v.x; X[2*i+1] = v.y; }
    float2 uv = ((const float2*)u)[idx];

    float xt0 = X[0]*th00 + X[1]*th10;
    float xt1 = X[0]*th01 + X[1]*th11;
    float ut0 = uv.x*th00 + uv.y*th10;
    float ut1 = uv.x*th01 + uv.y*th11;
    float s0 = sigf(xt0), s1 = sigf(xt1);

    float Mf00 = cf[0]+cl[0]+L1, Mf01 = cf[1]+cl[1], Mf10 = cf[2]+cl[2], Mf11 = cf[3]+cl[3]+L1;
    float Af0 = Mf00*s0 + Mf01*s1, Af1 = Mf10*s0 + Mf11*s1;
    float Au0 = cu[0]*ut0 + cu[1]*ut1, Au1 = cu[2]*ut0 + cu[3]*ut1;
    float Mb00 = cb[0]+cl[0], Mb01 = cb[1]+cl[1], Mb10 = cb[2]+cl[2], Mb11 = cb[3]+cl[3];
    float Abl0 = Mb00*s0 + Mb01*s1, Abl1 = Mb10*s0 + Mb11*s1;
    float A30 = (Mb00+L3)*s0 + Mb01*s1,  A31 = Mb10*s0 + (Mb11+L3)*s1;

    float F[22];
    F[0]  = X[0]  + dt*(X[10]-X[12]);
    F[1]  = X[1]  + dt*(X[11]-X[13]);
    F[2]  = X[2]  + dt*X[8];
    F[3]  = X[3]  + dt*X[9];
    F[4]  = X[4]  + dt*X[10];
    F[5]  = X[5]  + dt*X[11];
    F[6]  = X[6]  + dt*X[12];
    F[7]  = X[7]  + dt*X[13];
    F[8]  = X[8]  + dt*(He_te*(Af0+Au0) - 2.f*X[8]*ite  - X[2]*ite2);
    F[9]  = X[9]  + dt*(He_te*(Af1+Au1) - 2.f*X[9]*ite  - X[3]*ite2);
    F[10] = X[10] + dt*(He_te*(Abl0 + L2v*sigf(X[6])) - 2.f*X[10]*ite - X[4]*ite2);
    F[11] = X[11] + dt*(He_te*(Abl1 + L2v*sigf(X[7])) - 2.f*X[11]*ite - X[5]*ite2);
    F[12] = X[12] + dt*(Hi_ti*L4*sigf(X[14]) - 2.f*X[12]*iti - X[6]*iti2);
    F[13] = X[13] + dt*(Hi_ti*L4*sigf(X[15]) - 2.f*X[13]*iti - X[7]*iti2);
    F[14] = X[14] + dt*X[16];
    F[15] = X[15] + dt*X[17];
    F[16] = X[16] + dt*(He_te*A30 - 2.f*X[16]*ite - X[14]*ite2);
    F[17] = X[17] + dt*(He_te*A31 - 2.f*X[17]*ite - X[15]*ite2);
    F[18] = X[18]; F[19] = X[19]; F[20] = X[20]; F[21] = X[21];

    unsigned short op[32];
    #pragma unroll
    for (int s = 0; s < 4; ++s){
        #pragma unroll
        for (int e = 0; e < 8; ++e){
            int j = s*4 + (e & 3) + ((e >> 2) << 4);
            op[s*8+e] = (j < 22) ? f2bf(F[j]) : (unsigned short)0;
        }
    }
    uint4* dst = (uint4*)(feats + idx*32);
    #pragma unroll
    for (int q = 0; q < 4; ++q){
        uint4 v;
        v.x = (unsigned)op[q*8+0] | ((unsigned)op[q*8+1] << 16);
        v.y = (unsigned)op[q*8+2] | ((unsigned)op[q*8+3] << 16);
        v.z = (unsigned)op[q*8+4] | ((unsigned)op[q*8+5] << 16);
        v.w = (unsigned)op[q*8+6] | ((unsigned)op[q*8+7] << 16);
        dst[q] = v;
    }
}

// ---------------- Phase 2: LSTM scan, gate-pair-major (compiler-visible act) --
// 16 blocks x 4 batches, 8 waves; wave w owns j in [w*16, w*16+16).
// Step s: h ds_reads; 1 G_f MFMA (fills ds-latency); gates {2,0} chains (8 MFMA);
// early act (tg, si) — all builtins, so the scheduler can overlap it with the
// gates {1,3} chains (8 MFMA); final act (sf, so, c, h); h write; lgkm barrier.
__global__ __launch_bounds__(512, 1) void k_scan(
    const unsigned short* __restrict__ feats,
    const float* __restrict__ Wih, const float* __restrict__ Whh,
    const float* __restrict__ bih, const float* __restrict__ bhh,
    const float* __restrict__ Wlin, const float* __restrict__ blin,
    float* __restrict__ out)
{
    __shared__ __align__(16) unsigned short hist[16 * 576];   // 18.4 KB
    __shared__ __align__(16) unsigned short fch[64 * 32];     // 4 KB (feats of chk+1)

    const int tid = threadIdx.x;
    const int w  = tid >> 6;
    const int l  = tid & 63;
    const int lm = l & 15;
    const int lg = l >> 4;
    const int gb0 = blockIdx.x * 4;
    const int ar  = lm >> 2;

    for (int i = tid; i < 16*576/2; i += 512) ((unsigned*)hist)[i] = 0u;

    // ---- weight B-fragments (bf16) ----
    const int nj = w*16 + lm;
    s16x8 bw[4][5];
    #pragma unroll
    for (int t4 = 0; t4 < 4; ++t4){
        int n = t4*128 + nj;
        #pragma unroll
        for (int kc = 0; kc < 5; ++kc){
            #pragma unroll
            for (int j = 0; j < 8; ++j){
                int k = kc*32 + lg*4 + (j & 3) + ((j >> 2) << 4);
                float wv = 0.f;
                if (kc == 0){ if (k < 22) wv = Wih[n*22 + k]; }
                else        { wv = Whh[n*128 + (k - 32)]; }
                bw[t4][kc][j] = (short)f2bf(wv);
            }
        }
    }
    s16x8 wlf[4];
    #pragma unroll
    for (int kc = 0; kc < 4; ++kc){
        #pragma unroll
        for (int j = 0; j < 8; ++j){
            int k = kc*32 + lg*4 + (j & 3) + ((j >> 2) << 4);
            wlf[kc][j] = (lm < 2) ? (short)f2bf(Wlin[lm*128 + k]) : (short)0;
        }
    }
    const float blv = blin[l & 1];

    const float L2E = 1.44269504089f;
    float nLb0, nLb1, nLb3, b2g;
    {
        float bi = bih[0*128+nj] + bhh[0*128+nj];
        float bf = bih[1*128+nj] + bhh[1*128+nj];
        float bg = bih[2*128+nj] + bhh[2*128+nj];
        float bo = bih[3*128+nj] + bhh[3*128+nj];
        nLb0 = -L2E*bi; nLb1 = -L2E*bf; nLb3 = -L2E*bo; b2g = 2.f*L2E*bg;
    }

    // offsets
    const int aoff = ar*144 + lg*8;                   // h A-frag (shorts) within a hist slot
    const int khc = nj >> 5;
    const int hwoff = lg*144 + (khc*4 + ((nj >> 2) & 3))*8 + ((nj >> 4) & 1)*4 + (nj & 3);
    const int gfoff = ((lm & 3)*4 + (lm >> 2))*32 + lg*8;   // G_f A-frag; + mt*512 shorts

    // feats staging: threads < 256 own one 16B unit of the 4KB chunk
    const int u_t = tid >> 4, u_b = (tid >> 2) & 3, u_q = tid & 3;
    const unsigned short* psrc = feats + ((long)(gb0 + u_b)*T_ + u_t)*32 + u_q*8;
    unsigned short* const pdst = fch + (u_t*4 + u_b)*32 + u_q*8;

    const f32x4 Z4 = {0.f, 0.f, 0.f, 0.f};
    const int NCHK = T_/16;

    // ---- prologue: fch = feats(0); burst P = G_f(0); pend = feats(1) ----
    if (tid < 256){ uint4 t0 = *(const uint4*)psrc; *(uint4*)pdst = t0; }
    __syncthreads();
    f32x4 pA[4][4], pB[4][4];
    #pragma unroll
    for (int mt = 0; mt < 4; ++mt){
        s16x8 af = *(const s16x8*)(fch + mt*512 + gfoff);
        pA[mt][0] = __builtin_amdgcn_mfma_f32_16x16x32_bf16(af, bw[0][0], Z4, 0,0,0);
        pA[mt][1] = __builtin_amdgcn_mfma_f32_16x16x32_bf16(af, bw[1][0], Z4, 0,0,0);
        pA[mt][2] = __builtin_amdgcn_mfma_f32_16x16x32_bf16(af, bw[2][0], Z4, 0,0,0);
        pA[mt][3] = __builtin_amdgcn_mfma_f32_16x16x32_bf16(af, bw[3][0], Z4, 0,0,0);
    }
    uint4 pend = {0,0,0,0};
    if (tid < 256) pend = *(const uint4*)(psrc + (long)16*32);     // feats(1)
    __syncthreads();

    float c = 0.f;

    // boundary of chunk chk: fch <- pend (feats(chk+1)); y(chk-1); reissue pend
    auto boundary = [&](int chk){
        if (tid < 256) *(uint4*)pdst = pend;
        if (w >= 4 && chk > 0){
            const int mt = w - 4;
            const unsigned short* ap = hist + (mt*4 + (lm>>2))*576 + (lm&3)*144 + lg*8;
            s16x8 q0 = *(const s16x8*)(ap +  0);
            s16x8 q1 = *(const s16x8*)(ap + 32);
            s16x8 q2 = *(const s16x8*)(ap + 64);
            s16x8 q3 = *(const s16x8*)(ap + 96);
            f32x4 acc = __builtin_amdgcn_mfma_f32_16x16x32_bf16(q0, wlf[0], Z4, 0,0,0);
            acc = __builtin_amdgcn_mfma_f32_16x16x32_bf16(q1, wlf[1], acc, 0,0,0);
            acc = __builtin_amdgcn_mfma_f32_16x16x32_bf16(q2, wlf[2], acc, 0,0,0);
            acc = __builtin_amdgcn_mfma_f32_16x16x32_bf16(q3, wlf[3], acc, 0,0,0);
            if (lm < 2){
                const int tY = (chk - 1)*16 + mt*4 + lg;
                #pragma unroll
                for (int r = 0; r < 4; ++r)
                    out[((long)(gb0 + r)*T_ + tY)*2 + lm] = acc[r] + blv;
            }
        }
        {
            long nk = (chk < NCHK-2) ? (chk + 2) : (NCHK-1);
            if (tid < 256) pend = *(const uint4*)(psrc + nk*(long)(16*32));
        }
        bar_lgkm();
    };

    // 16 steps of one chunk: consume P, build PN = G_f(chk+1)
    auto steps = [&](f32x4 (&P)[4][4], f32x4 (&PN)[4][4]){
        s16x8 afg;
        #pragma unroll
        for (int s = 0; s < 16; ++s){
            const unsigned short* hp = hist + ((s+15)&15)*576 + aoff;
            s16x8 h1 = *(const s16x8*)(hp +  0);
            s16x8 h2 = *(const s16x8*)(hp + 32);
            s16x8 h3 = *(const s16x8*)(hp + 64);
            s16x8 h4 = *(const s16x8*)(hp + 96);
            if ((s & 3) == 0) afg = *(const s16x8*)(fch + (s>>2)*512 + gfoff);
            // fill the ds-latency window with the G_f MFMA for next chunk
            PN[s>>2][s&3] = __builtin_amdgcn_mfma_f32_16x16x32_bf16(afg, bw[s&3][0], Z4, 0,0,0);
            __builtin_amdgcn_sched_barrier(0);

            // ---- gates {2,0} chains first (their act is the long pole) ----
            f32x4 a2 = __builtin_amdgcn_mfma_f32_16x16x32_bf16(h1, bw[2][1], Z4, 0,0,0);
            f32x4 a0 = __builtin_amdgcn_mfma_f32_16x16x32_bf16(h1, bw[0][1], Z4, 0,0,0);
            a2 = __builtin_amdgcn_mfma_f32_16x16x32_bf16(h2, bw[2][2], a2, 0,0,0);
            a0 = __builtin_amdgcn_mfma_f32_16x16x32_bf16(h2, bw[0][2], a0, 0,0,0);
            a2 = __builtin_amdgcn_mfma_f32_16x16x32_bf16(h3, bw[2][3], a2, 0,0,0);
            a0 = __builtin_amdgcn_mfma_f32_16x16x32_bf16(h3, bw[0][3], a0, 0,0,0);
            a2 = __builtin_amdgcn_mfma_f32_16x16x32_bf16(h4, bw[2][4], a2, 0,0,0);
            a0 = __builtin_amdgcn_mfma_f32_16x16x32_bf16(h4, bw[0][4], a0, 0,0,0);

            // early act: tg (g-gate) and si (i-gate) — compiler-visible ops only,
            // free to overlap with the {1,3} MFMA issue below
            float gg  = a2[0] + P[s>>2][2][s&3];
            float eg  = fexp2(fmaf(gg, 2.f*L2E, b2g));
            float tg_ = fmaf(-2.f, frcp(1.f + eg), 1.f);
            float gi  = a0[0] + P[s>>2][0][s&3];
            float si  = frcp(1.f + fexp2(fmaf(gi, -L2E, nLb0)));

            // ---- gates {1,3} chains ----
            f32x4 a1 = __builtin_amdgcn_mfma_f32_16x16x32_bf16(h1, bw[1][1], Z4, 0,0,0);
            f32x4 a3 = __builtin_amdgcn_mfma_f32_16x16x32_bf16(h1, bw[3][1], Z4, 0,0,0);
            a1 = __builtin_amdgcn_mfma_f32_16x16x32_bf16(h2, bw[1][2], a1, 0,0,0);
            a3 = __builtin_amdgcn_mfma_f32_16x16x32_bf16(h2, bw[3][2], a3, 0,0,0);
            a1 = __builtin_amdgcn_mfma_f32_16x16x32_bf16(h3, bw[1][3], a1, 0,0,0);
            a3 = __builtin_amdgcn_mfma_f32_16x16x32_bf16(h3, bw[3][3], a3, 0,0,0);
            a1 = __builtin_amdgcn_mfma_f32_16x16x32_bf16(h4, bw[1][4], a1, 0,0,0);
            a3 = __builtin_amdgcn_mfma_f32_16x16x32_bf16(h4, bw[3][4], a3, 0,0,0);

            // final act: sf, so, c-update, h
            float gfo = a1[0] + P[s>>2][1][s&3];
            float sf  = frcp(1.f + fexp2(fmaf(gfo, -L2E, nLb1)));
            float go  = a3[0] + P[s>>2][3][s&3];
            float so  = frcp(1.f + fexp2(fmaf(go,  -L2E, nLb3)));
            c = sf*c + si*tg_;
            float ec  = fexp2(c * (2.f*L2E));
            float tc_ = fmaf(-2.f, frcp(1.f + ec), 1.f);
            float h   = so * tc_;

            hist[s*576 + hwoff] = f2bf(h);

            bar_lgkm();
        }
    };

    for (int c2 = 0; c2 < NCHK/2; ++c2){
        boundary(2*c2);       steps(pA, pB);
        boundary(2*c2 + 1);   steps(pB, pA);
    }

    // final y window (chunk NCHK-1) — hist intact after last step barrier
    if (w >= 4){
        const int mt = w - 4;
        const unsigned short* ap = hist + (mt*4 + (lm>>2))*576 + (lm&3)*144 + lg*8;
        s16x8 q0 = *(const s16x8*)(ap +  0);
        s16x8 q1 = *(const s16x8*)(ap + 32);
        s16x8 q2 = *(const s16x8*)(ap + 64);
        s16x8 q3 = *(const s16x8*)(ap + 96);
        f32x4 acc = __builtin_amdgcn_mfma_f32_16x16x32_bf16(q0, wlf[0], Z4, 0,0,0);
        acc = __builtin_amdgcn_mfma_f32_16x16x32_bf16(q1, wlf[1], acc, 0,0,0);
        acc = __builtin_amdgcn_mfma_f32_16x16x32_bf16(q2, wlf[2], acc, 0,0,0);
        acc = __builtin_amdgcn_mfma_f32_16x16x32_bf16(q3, wlf[3], acc, 0,0,0);
        if (lm < 2){
            const int tY = (T_ - 16) + mt*4 + lg;
            #pragma unroll
            for (int r = 0; r < 4; ++r)
                out[((long)(gb0 + r)*T_ + tY)*2 + lm] = acc[r] + blv;
        }
    }
}

extern "C" void kernel_launch(void* const* d_in, const int* in_sizes, int n_in,
                              void* d_out, int out_size, void* d_ws, size_t ws_size,
                              hipStream_t stream)
{
    const float* x     = (const float*)d_in[0];
    const float* u     = (const float*)d_in[1];
    const float* dtp   = (const float*)d_in[2];
    const float* theta = (const float*)d_in[3];
    const float* He    = (const float*)d_in[4];
    const float* taue  = (const float*)d_in[5];
    const float* Hi    = (const float*)d_in[6];
    const float* taui  = (const float*)d_in[7];
    const float* l1    = (const float*)d_in[8];
    const float* l2    = (const float*)d_in[9];
    const float* l3    = (const float*)d_in[10];
    const float* l4    = (const float*)d_in[11];
    const float* Cf    = (const float*)d_in[12];
    const float* Cl    = (const float*)d_in[13];
    const float* Cu    = (const float*)d_in[14];
    const float* Cb    = (const float*)d_in[15];
    const float* Wih   = (const float*)d_in[16];
    const float* Whh   = (const float*)d_in[17];
    const float* bih   = (const float*)d_in[18];
    const float* bhh   = (const float*)d_in[19];
    const float* Wlin  = (const float*)d_in[20];
    const float* blin  = (const float*)d_in[21];

    unsigned short* feats = (unsigned short*)d_ws;   // B*T*32 bf16 = 16 MiB (permuted)

    k_feats<<<(B_*T_)/256, 256, 0, stream>>>(x,u,dtp,theta,He,taue,Hi,taui,
                                             l1,l2,l3,l4,Cf,Cl,Cu,Cb,feats);
    k_scan<<<16, 512, 0, stream>>>(feats, Wih, Whh, bih, bhh, Wlin, blin, (float*)d_out);
}